// Round 4
// baseline (226.582 us; speedup 1.0000x reference)
//
#include <hip/hip_runtime.h>
#include <math.h>

// Problem constants (fixed by the reference setup)
#define B_ 4
#define N_ 6400
#define D_ 32
#define TJ 256          // j-chunk staged in LDS (k_pass), also combine chunking
#define NCHJ 25         // N_/TJ
#define TI 128          // anchors per k_pass block (4 waves x 2 i-tiles x 16)

typedef __attribute__((ext_vector_type(4))) float f32x4;
typedef __attribute__((ext_vector_type(8))) short bf16x8;

static constexpr float MARGIN_ = 0.3f;

// monotone float<->uint map so atomicMax(uint) == float max
__device__ __forceinline__ unsigned fmap(float f) {
    unsigned u = __float_as_uint(f);
    return (u & 0x80000000u) ? ~u : (u | 0x80000000u);
}
__device__ __forceinline__ float funmap(unsigned u) {
    return (u & 0x80000000u) ? __uint_as_float(u ^ 0x80000000u)
                             : __uint_as_float(~u);
}
#define NEG_INF_MAPPED 0x007FFFFFu   // fmap(-inf)

// round-to-nearest-even f32 -> bf16
__device__ __forceinline__ unsigned short f2bf(float f) {
    unsigned u = __float_as_uint(f);
    unsigned r = u + 0x7fffu + ((u >> 16) & 1u);
    return (unsigned short)(r >> 16);
}
__device__ __forceinline__ float bf2f(unsigned short h) {
    return __uint_as_float(((unsigned)h) << 16);
}
// unpack packed bf16 pair (elem even in low 16, odd in high 16)
__device__ __forceinline__ void bf2x(unsigned u, float& e0, float& e1) {
    e0 = __uint_as_float(u << 16);
    e1 = __uint_as_float(u & 0xffff0000u);
}

// ---------------- Kernel 1: compact + gather + normalize + hi/lo split ----------------
// One block per batch (1024 thr). Ballot-scan compaction preserving order,
// then gather/normalize/split the ~M fg rows (~3 rows per thread).
__global__ __launch_bounds__(1024) void k_compact(const float* __restrict__ pred,
                                                  const int* __restrict__ gt,
                                                  const int* __restrict__ fg,
                                                  unsigned short* __restrict__ hi_g,
                                                  unsigned short* __restrict__ lo_g,
                                                  int* __restrict__ clist,
                                                  int* __restrict__ cg,
                                                  int* __restrict__ Marr,
                                                  unsigned* __restrict__ bestArr,
                                                  float* __restrict__ accum) {
    int b = blockIdx.x;
    int tid = threadIdx.x;
    if (b == 0 && tid == 0) { accum[0] = 0.0f; ((int*)accum)[1] = 0; }

    for (int r = tid; r < N_; r += 1024) bestArr[b * N_ + r] = NEG_INF_MAPPED;

    __shared__ int wsum[16];
    __shared__ int sbase;
    if (tid == 0) sbase = 0;
    __syncthreads();

    int lane = tid & 63, wv = tid >> 6;
    for (int t0 = 0; t0 < N_; t0 += 1024) {
        int idx = t0 + tid;
        bool flag = (idx < N_) && (fg[b * N_ + idx] != 0);
        unsigned long long mask = __ballot(flag);
        int lp = __popcll(mask & ((1ull << lane) - 1ull));
        if (lane == 0) wsum[wv] = __popcll(mask);
        __syncthreads();
        int woff = 0, btot = 0;
        #pragma unroll
        for (int w = 0; w < 16; ++w) { if (w < wv) woff += wsum[w]; btot += wsum[w]; }
        int base = sbase;
        if (flag) {
            int pos = base + woff + lp;
            clist[b * N_ + pos] = idx;
            cg[b * N_ + pos] = gt[b * N_ + idx];
        }
        __syncthreads();
        if (tid == 0) sbase = base + btot;
        __syncthreads();
    }
    int M = sbase;
    if (tid == 0) Marr[b] = M;

    // gather + normalize + bf16 hi/lo split for compacted rows
    for (int r = tid; r < M; r += 1024) {
        int orig = clist[b * N_ + r];
        const float4* s4 = (const float4*)(pred + ((size_t)b * N_ + orig) * D_);
        float f[32];
        float ssq = 0.0f;
        #pragma unroll
        for (int k = 0; k < 8; ++k) {
            float4 q = s4[k];
            f[k * 4] = q.x; f[k * 4 + 1] = q.y; f[k * 4 + 2] = q.z; f[k * 4 + 3] = q.w;
            ssq += q.x * q.x + q.y * q.y + q.z * q.z + q.w * q.w;
        }
        float inv = 1.0f / fmaxf(sqrtf(ssq), 1e-12f);
        unsigned hw[16], lw[16];
        #pragma unroll
        for (int k = 0; k < 16; ++k) {
            float x0 = f[2 * k] * inv, x1 = f[2 * k + 1] * inv;
            unsigned short h0 = f2bf(x0), h1 = f2bf(x1);
            unsigned short l0 = f2bf(x0 - bf2f(h0)), l1 = f2bf(x1 - bf2f(h1));
            hw[k] = (unsigned)h0 | ((unsigned)h1 << 16);
            lw[k] = (unsigned)l0 | ((unsigned)l1 << 16);
        }
        uint4* dh = (uint4*)(hi_g + ((size_t)b * N_ + r) * 32);
        uint4* dl = (uint4*)(lo_g + ((size_t)b * N_ + r) * 32);
        #pragma unroll
        for (int k = 0; k < 4; ++k) {
            dh[k] = make_uint4(hw[4 * k], hw[4 * k + 1], hw[4 * k + 2], hw[4 * k + 3]);
            dl[k] = make_uint4(lw[4 * k], lw[4 * k + 1], lw[4 * k + 2], lw[4 * k + 3]);
        }
    }
}

// ---------------- Kernel 2: MFMA pair pass (unchanged from R3, verified) ----------------
// grid = (ceil(N/TI), ceil(N/TJ), B). Wave covers 2 i-tiles of 16 anchors.
// S-tile = 16x16 via mfma_f32_16x16x32_bf16, 3 terms (hi*hi + hi*lo + lo*hi).
// C/D layout: col = lane&15, row = (lane>>4)*4 + reg  [m89-verified].
__global__ __launch_bounds__(256) void k_pass(const unsigned short* __restrict__ hi_g,
                                              const unsigned short* __restrict__ lo_g,
                                              const int* __restrict__ cg,
                                              const int* __restrict__ Marr,
                                              unsigned short* __restrict__ p_cnt,
                                              unsigned* __restrict__ bestArr) {
    int b = blockIdx.z;
    int M = Marr[b];
    int i0 = blockIdx.x * TI;
    int j0 = blockIdx.y * TJ;
    if (i0 >= M || j0 >= M) return;   // block-uniform exit

    // LDS rows padded to 80 B (40 shorts): 16-lane frag reads = 2-way banks (free)
    __shared__ __align__(16) unsigned short sc_hi[TJ * 40];  // 20 KB
    __shared__ __align__(16) unsigned short sc_lo[TJ * 40];  // 20 KB
    __shared__ int sg[TJ];
    int t = threadIdx.x;

    {
        int j = j0 + t;
        sg[t] = (j < M) ? cg[b * N_ + j] : -1;
    }
    {   // stage: thread -> (row = p*64 + t>>2, 16B seg = t&3); coalesced global reads
        int seg = t & 3, r0 = t >> 2;
        #pragma unroll
        for (int p = 0; p < 4; ++p) {
            int row = p * 64 + r0;
            int j = j0 + row;
            uint4 vh = make_uint4(0u, 0u, 0u, 0u), vl = make_uint4(0u, 0u, 0u, 0u);
            if (j < M) {
                vh = *(const uint4*)(hi_g + ((size_t)b * N_ + j) * 32 + seg * 8);
                vl = *(const uint4*)(lo_g + ((size_t)b * N_ + j) * 32 + seg * 8);
            }
            *(uint4*)(sc_hi + row * 40 + seg * 8) = vh;
            *(uint4*)(sc_lo + row * 40 + seg * 8) = vl;
        }
    }
    __syncthreads();

    int lane = t & 63, w = t >> 6;
    int r = lane & 15, quad = lane >> 4;
    int ib = i0 + w * 32;            // this wave's 32 anchors (2 i-tiles)

    bf16x8 a_hi[2], a_lo[2];
    int gt_i[2][4];
    #pragma unroll
    for (int it = 0; it < 2; ++it) {
        int i = ib + it * 16 + r;
        bf16x8 zh = {0, 0, 0, 0, 0, 0, 0, 0};
        a_hi[it] = zh; a_lo[it] = zh;
        if (i < M) {
            a_hi[it] = *(const bf16x8*)(hi_g + ((size_t)b * N_ + i) * 32 + quad * 8);
            a_lo[it] = *(const bf16x8*)(lo_g + ((size_t)b * N_ + i) * 32 + quad * 8);
        }
        #pragma unroll
        for (int r4 = 0; r4 < 4; ++r4) {
            int ia = ib + it * 16 + quad * 4 + r4;
            gt_i[it][r4] = (ia < M) ? cg[b * N_ + ia] : -2;
        }
    }

    float best[2][4];
    int cnt[2][4];
    #pragma unroll
    for (int it = 0; it < 2; ++it)
        #pragma unroll
        for (int r4 = 0; r4 < 4; ++r4) { best[it][r4] = -INFINITY; cnt[it][r4] = 0; }

    int jrows = min(TJ, M - j0);
    int ntile = (jrows + 15) >> 4;
    for (int jt = 0; jt < ntile; ++jt) {
        int gtj = sg[jt * 16 + r];
        bf16x8 bh = *(const bf16x8*)(sc_hi + (jt * 16 + r) * 40 + quad * 8);
        bf16x8 bl = *(const bf16x8*)(sc_lo + (jt * 16 + r) * 40 + quad * 8);
        bool jv = (gtj >= 0);
        #pragma unroll
        for (int it = 0; it < 2; ++it) {
            f32x4 acc = {0.f, 0.f, 0.f, 0.f};
            acc = __builtin_amdgcn_mfma_f32_16x16x32_bf16(a_hi[it], bh, acc, 0, 0, 0);
            acc = __builtin_amdgcn_mfma_f32_16x16x32_bf16(a_hi[it], bl, acc, 0, 0, 0);
            acc = __builtin_amdgcn_mfma_f32_16x16x32_bf16(a_lo[it], bh, acc, 0, 0, 0);
            #pragma unroll
            for (int r4 = 0; r4 < 4; ++r4) {
                float s = acc[r4];
                bool same = (gtj == gt_i[it][r4]);
                float sm = (same || !jv) ? -INFINITY : s;
                best[it][r4] = fmaxf(best[it][r4], sm);
                cnt[it][r4] += same ? 1 : 0;   // self-pair included; fixed in combine
            }
        }
    }

    #pragma unroll
    for (int it = 0; it < 2; ++it) {
        #pragma unroll
        for (int r4 = 0; r4 < 4; ++r4) {
            float bb = best[it][r4];
            int cc = cnt[it][r4];
            #pragma unroll
            for (int mk = 1; mk < 16; mk <<= 1) {
                bb = fmaxf(bb, __shfl_xor(bb, mk));
                cc += __shfl_xor(cc, mk);
            }
            if (r == 0) {
                int ia = ib + it * 16 + quad * 4 + r4;
                if (ia < M) {
                    p_cnt[((size_t)b * N_ + ia) * NCHJ + blockIdx.y] = (unsigned short)cc;
                    if (bb > -INFINITY) atomicMax(&bestArr[b * N_ + ia], fmap(bb));
                }
            }
        }
    }
}

// ---------------- Kernel 3: combine — ONE WAVE PER ANCHOR ----------------
// Block = 256 thr = 4 waves = 4 anchors. Chunk-locate via 64-lane shuffle scan
// over per-chunk counts; positive rescan via 4 ballot/popcount steps; pos-dot
// lane-parallel over 16 lanes. All wave ops in wave-uniform branches.
__global__ __launch_bounds__(256) void k_combine(const unsigned short* __restrict__ hi_g,
                                                 const unsigned short* __restrict__ lo_g,
                                                 const int* __restrict__ cg,
                                                 const int* __restrict__ clist,
                                                 const int* __restrict__ Marr,
                                                 const float* __restrict__ pos_rand,
                                                 const unsigned short* __restrict__ p_cnt,
                                                 const unsigned* __restrict__ bestArr,
                                                 float* __restrict__ accum) {
    int b = blockIdx.y;
    int M = Marr[b];
    int t = threadIdx.x;
    int w = t >> 6, lane = t & 63;
    int i = blockIdx.x * 4 + w;           // this wave's anchor (wave-uniform)

    float contrib = 0.0f;
    int vflag = 0;

    if (i < M) {                           // wave-uniform
        int nchj = (M + TJ - 1) / TJ;
        int ich = i / TJ;
        const unsigned short* pc = p_cnt + ((size_t)b * N_ + i) * NCHJ;
        int c_s = 0;
        if (lane < nchj) c_s = (int)pc[lane] - (lane == ich ? 1 : 0);  // self removed
        // inclusive 64-lane scan
        int P = c_s;
        #pragma unroll
        for (int off = 1; off < 64; off <<= 1) {
            int n = __shfl_up(P, off);
            if (lane >= off) P += n;
        }
        int num_pos = __shfl(P, 63);
        unsigned bu = bestArr[b * N_ + i];
        if (num_pos >= 1 && bu != NEG_INF_MAPPED) {   // wave-uniform
            float best = funmap(bu);
            int orig = clist[b * N_ + i];
            float u = pos_rand[b * N_ + orig];
            int pcx = (int)floorf(u * (float)num_pos);   // matches jnp f32 math
            int hi2 = num_pos - 1;
            pcx = pcx < 0 ? 0 : (pcx > hi2 ? hi2 : pcx);
            int target = pcx + 1;
            // first chunk where inclusive prefix reaches target
            unsigned long long selm = __ballot(P >= target);
            int sstar = __ffsll((unsigned long long)selm) - 1;
            int c0 = (sstar > 0) ? __shfl(P, sstar - 1) : 0;
            int need = target - c0;       // wave-uniform, >= 1
            int jstart = sstar * TJ;
            int jend = min(jstart + TJ, M);
            int ga = cg[b * N_ + i];
            int posj = -1;
            #pragma unroll
            for (int k = 0; k < 4; ++k) {
                if (posj >= 0) continue;
                int j = jstart + k * 64 + lane;
                bool flag = (j < jend) && (cg[b * N_ + j] == ga) && (j != i);
                unsigned long long mk = __ballot(flag);
                int tot = __popcll(mk);
                if (need <= tot) {
                    int pfx = __popcll(mk & ((1ull << lane) - 1ull));
                    unsigned long long sel = __ballot(flag && (pfx == need - 1));
                    posj = jstart + k * 64 + (__ffsll((unsigned long long)sel) - 1);
                } else {
                    need -= tot;
                }
            }
            // lane-parallel dot over the 16 packed-bf16 pairs (fp32 reconstruct)
            float part = 0.0f;
            if (lane < 16) {
                unsigned xh = ((const unsigned*)(hi_g + ((size_t)b * N_ + i) * 32))[lane];
                unsigned xl = ((const unsigned*)(lo_g + ((size_t)b * N_ + i) * 32))[lane];
                unsigned yh = ((const unsigned*)(hi_g + ((size_t)b * N_ + posj) * 32))[lane];
                unsigned yl = ((const unsigned*)(lo_g + ((size_t)b * N_ + posj) * 32))[lane];
                float a0, a1, b0, b1, c0f, c1f, d0, d1;
                bf2x(xh, a0, a1); bf2x(xl, b0, b1);
                bf2x(yh, c0f, c1f); bf2x(yl, d0, d1);
                part = fmaf(a0 + b0, c0f + d0, (a1 + b1) * (c1f + d1));
            }
            #pragma unroll
            for (int mk2 = 1; mk2 < 16; mk2 <<= 1) part += __shfl_xor(part, mk2);
            float dot = part;   // lane 0's value valid; contrib used from lane 0 only
            float pos_d = sqrtf(fmaxf(2.f - 2.f * dot, 0.f) + 1e-12f);
            float neg_d = sqrtf(fmaxf(2.f - 2.f * best, 0.f) + 1e-12f);
            contrib = fmaxf(pos_d - neg_d + MARGIN_, 0.0f);
            vflag = 1;
        }
    }

    __shared__ float swv[4];
    __shared__ int swc[4];
    if (lane == 0) { swv[w] = contrib; swc[w] = vflag; }
    __syncthreads();
    if (t == 0) {
        float tv = swv[0] + swv[1] + swv[2] + swv[3];
        int tc = swc[0] + swc[1] + swc[2] + swc[3];
        if (tc > 0) {
            atomicAdd(&accum[0], tv);
            atomicAdd(((int*)accum) + 1, tc);
        }
    }
}

// ---------------- Kernel 4: finalize ----------------
__global__ void k_final(const float* __restrict__ accum, float* __restrict__ out) {
    float t = accum[0];
    int n = ((const int*)accum)[1];
    out[0] = (n > 0) ? (t / (float)(n > 1 ? n : 1)) : 0.0f;
}

// ---------------- launch ----------------
extern "C" void kernel_launch(void* const* d_in, const int* in_sizes, int n_in,
                              void* d_out, int out_size, void* d_ws, size_t ws_size,
                              hipStream_t stream) {
    const float* pred     = (const float*)d_in[0];
    const float* pos_rand = (const float*)d_in[1];
    const int*   gt       = (const int*)d_in[2];
    const int*   fg       = (const int*)d_in[3];
    float* out = (float*)d_out;

    char* ws = (char*)d_ws;
    // layout (bytes):
    //   hi_g     : 0         .. 1,638,400   (B*N*32 bf16)
    //   lo_g     : 1,638,400 .. 3,276,800
    //   clist    : 3,276,800 .. 3,379,200   (B*N i32)
    //   cg       : 3,379,200 .. 3,481,600   (B*N i32)
    //   Marr     : 3,481,600 .. 3,481,664
    //   bestArr  : 3,482,688 .. 3,585,088   (B*N u32)
    //   p_cnt    : 3,585,088 .. 4,865,088   (B*N*NCHJ u16)
    //   accum    : 4,865,088 (+8)
    unsigned short* hi_g    = (unsigned short*)(ws);
    unsigned short* lo_g    = (unsigned short*)(ws + 1638400);
    int*            clist   = (int*)(ws + 3276800);
    int*            cg      = (int*)(ws + 3379200);
    int*            Marr    = (int*)(ws + 3481600);
    unsigned*       bestArr = (unsigned*)(ws + 3482688);
    unsigned short* p_cnt   = (unsigned short*)(ws + 3585088);
    float*          accum   = (float*)(ws + 4865088);

    k_compact<<<B_, 1024, 0, stream>>>(pred, gt, fg, hi_g, lo_g, clist, cg, Marr, bestArr, accum);
    dim3 gp((N_ + TI - 1) / TI, (N_ + TJ - 1) / TJ, B_);
    k_pass<<<gp, 256, 0, stream>>>(hi_g, lo_g, cg, Marr, p_cnt, bestArr);
    dim3 gc((N_ + 3) / 4, B_);
    k_combine<<<gc, 256, 0, stream>>>(hi_g, lo_g, cg, clist, Marr, pos_rand, p_cnt, bestArr, accum);
    k_final<<<1, 1, 0, stream>>>(accum, out);
}

// Round 5
// 156.261 us; speedup vs baseline: 1.4500x; 1.4500x over previous
//
#include <hip/hip_runtime.h>
#include <math.h>

// Problem constants (fixed by the reference setup)
#define B_ 4
#define N_ 6400
#define D_ 32
#define TJ 256          // j-chunk staged in LDS (k_pass), also combine chunking
#define NCHJ 25         // N_/TJ
#define TI 128          // anchors per k_pass block (4 waves x 2 i-tiles x 16)

typedef __attribute__((ext_vector_type(4))) float f32x4;
typedef __attribute__((ext_vector_type(8))) short bf16x8;

static constexpr float MARGIN_ = 0.3f;

// monotone float<->uint map so atomicMax(uint) == float max
__device__ __forceinline__ unsigned fmap(float f) {
    unsigned u = __float_as_uint(f);
    return (u & 0x80000000u) ? ~u : (u | 0x80000000u);
}
__device__ __forceinline__ float funmap(unsigned u) {
    return (u & 0x80000000u) ? __uint_as_float(u ^ 0x80000000u)
                             : __uint_as_float(~u);
}
#define NEG_INF_MAPPED 0x007FFFFFu   // fmap(-inf)

// round-to-nearest-even f32 -> bf16
__device__ __forceinline__ unsigned short f2bf(float f) {
    unsigned u = __float_as_uint(f);
    unsigned r = u + 0x7fffu + ((u >> 16) & 1u);
    return (unsigned short)(r >> 16);
}
__device__ __forceinline__ float bf2f(unsigned short h) {
    return __uint_as_float(((unsigned)h) << 16);
}
// unpack packed bf16 pair (elem even in low 16, odd in high 16)
__device__ __forceinline__ void bf2x(unsigned u, float& e0, float& e1) {
    e0 = __uint_as_float(u << 16);
    e1 = __uint_as_float(u & 0xffff0000u);
}

// ---------------- Kernel 1: compact + gather + normalize + hi/lo split ----------------
__global__ __launch_bounds__(1024) void k_compact(const float* __restrict__ pred,
                                                  const int* __restrict__ gt,
                                                  const int* __restrict__ fg,
                                                  unsigned short* __restrict__ hi_g,
                                                  unsigned short* __restrict__ lo_g,
                                                  int* __restrict__ clist,
                                                  int* __restrict__ cg,
                                                  int* __restrict__ Marr,
                                                  unsigned* __restrict__ bestArr) {
    int b = blockIdx.x;
    int tid = threadIdx.x;

    for (int r = tid; r < N_; r += 1024) bestArr[b * N_ + r] = NEG_INF_MAPPED;

    __shared__ int wsum[16];
    __shared__ int sbase;
    if (tid == 0) sbase = 0;
    __syncthreads();

    int lane = tid & 63, wv = tid >> 6;
    for (int t0 = 0; t0 < N_; t0 += 1024) {
        int idx = t0 + tid;
        bool flag = (idx < N_) && (fg[b * N_ + idx] != 0);
        unsigned long long mask = __ballot(flag);
        int lp = __popcll(mask & ((1ull << lane) - 1ull));
        if (lane == 0) wsum[wv] = __popcll(mask);
        __syncthreads();
        int woff = 0, btot = 0;
        #pragma unroll
        for (int w = 0; w < 16; ++w) { if (w < wv) woff += wsum[w]; btot += wsum[w]; }
        int base = sbase;
        if (flag) {
            int pos = base + woff + lp;
            clist[b * N_ + pos] = idx;
            cg[b * N_ + pos] = gt[b * N_ + idx];
        }
        __syncthreads();
        if (tid == 0) sbase = base + btot;
        __syncthreads();
    }
    int M = sbase;
    if (tid == 0) Marr[b] = M;

    // gather + normalize + bf16 hi/lo split for compacted rows
    for (int r = tid; r < M; r += 1024) {
        int orig = clist[b * N_ + r];
        const float4* s4 = (const float4*)(pred + ((size_t)b * N_ + orig) * D_);
        float f[32];
        float ssq = 0.0f;
        #pragma unroll
        for (int k = 0; k < 8; ++k) {
            float4 q = s4[k];
            f[k * 4] = q.x; f[k * 4 + 1] = q.y; f[k * 4 + 2] = q.z; f[k * 4 + 3] = q.w;
            ssq += q.x * q.x + q.y * q.y + q.z * q.z + q.w * q.w;
        }
        float inv = 1.0f / fmaxf(sqrtf(ssq), 1e-12f);
        unsigned hw[16], lw[16];
        #pragma unroll
        for (int k = 0; k < 16; ++k) {
            float x0 = f[2 * k] * inv, x1 = f[2 * k + 1] * inv;
            unsigned short h0 = f2bf(x0), h1 = f2bf(x1);
            unsigned short l0 = f2bf(x0 - bf2f(h0)), l1 = f2bf(x1 - bf2f(h1));
            hw[k] = (unsigned)h0 | ((unsigned)h1 << 16);
            lw[k] = (unsigned)l0 | ((unsigned)l1 << 16);
        }
        uint4* dh = (uint4*)(hi_g + ((size_t)b * N_ + r) * 32);
        uint4* dl = (uint4*)(lo_g + ((size_t)b * N_ + r) * 32);
        #pragma unroll
        for (int k = 0; k < 4; ++k) {
            dh[k] = make_uint4(hw[4 * k], hw[4 * k + 1], hw[4 * k + 2], hw[4 * k + 3]);
            dl[k] = make_uint4(lw[4 * k], lw[4 * k + 1], lw[4 * k + 2], lw[4 * k + 3]);
        }
    }
}

// ---------------- Kernel 2: MFMA pair pass (verified since R3) ----------------
// grid = (ceil(N/TI), ceil(N/TJ), B). Wave covers 2 i-tiles of 16 anchors.
// S-tile = 16x16 via mfma_f32_16x16x32_bf16, 3 terms (hi*hi + hi*lo + lo*hi).
// C/D layout: col = lane&15, row = (lane>>4)*4 + reg  [m89-verified].
__global__ __launch_bounds__(256) void k_pass(const unsigned short* __restrict__ hi_g,
                                              const unsigned short* __restrict__ lo_g,
                                              const int* __restrict__ cg,
                                              const int* __restrict__ Marr,
                                              unsigned short* __restrict__ p_cnt,
                                              unsigned* __restrict__ bestArr) {
    int b = blockIdx.z;
    int M = Marr[b];
    int i0 = blockIdx.x * TI;
    int j0 = blockIdx.y * TJ;
    if (i0 >= M || j0 >= M) return;   // block-uniform exit

    // LDS rows padded to 80 B (40 shorts): 16-lane frag reads = 2-way banks (free)
    __shared__ __align__(16) unsigned short sc_hi[TJ * 40];  // 20 KB
    __shared__ __align__(16) unsigned short sc_lo[TJ * 40];  // 20 KB
    __shared__ int sg[TJ];
    int t = threadIdx.x;

    {
        int j = j0 + t;
        sg[t] = (j < M) ? cg[b * N_ + j] : -1;
    }
    {   // stage: thread -> (row = p*64 + t>>2, 16B seg = t&3); coalesced global reads
        int seg = t & 3, r0 = t >> 2;
        #pragma unroll
        for (int p = 0; p < 4; ++p) {
            int row = p * 64 + r0;
            int j = j0 + row;
            uint4 vh = make_uint4(0u, 0u, 0u, 0u), vl = make_uint4(0u, 0u, 0u, 0u);
            if (j < M) {
                vh = *(const uint4*)(hi_g + ((size_t)b * N_ + j) * 32 + seg * 8);
                vl = *(const uint4*)(lo_g + ((size_t)b * N_ + j) * 32 + seg * 8);
            }
            *(uint4*)(sc_hi + row * 40 + seg * 8) = vh;
            *(uint4*)(sc_lo + row * 40 + seg * 8) = vl;
        }
    }
    __syncthreads();

    int lane = t & 63, w = t >> 6;
    int r = lane & 15, quad = lane >> 4;
    int ib = i0 + w * 32;            // this wave's 32 anchors (2 i-tiles)

    bf16x8 a_hi[2], a_lo[2];
    int gt_i[2][4];
    #pragma unroll
    for (int it = 0; it < 2; ++it) {
        int i = ib + it * 16 + r;
        bf16x8 zh = {0, 0, 0, 0, 0, 0, 0, 0};
        a_hi[it] = zh; a_lo[it] = zh;
        if (i < M) {
            a_hi[it] = *(const bf16x8*)(hi_g + ((size_t)b * N_ + i) * 32 + quad * 8);
            a_lo[it] = *(const bf16x8*)(lo_g + ((size_t)b * N_ + i) * 32 + quad * 8);
        }
        #pragma unroll
        for (int r4 = 0; r4 < 4; ++r4) {
            int ia = ib + it * 16 + quad * 4 + r4;
            gt_i[it][r4] = (ia < M) ? cg[b * N_ + ia] : -2;
        }
    }

    float best[2][4];
    int cnt[2][4];
    #pragma unroll
    for (int it = 0; it < 2; ++it)
        #pragma unroll
        for (int r4 = 0; r4 < 4; ++r4) { best[it][r4] = -INFINITY; cnt[it][r4] = 0; }

    int jrows = min(TJ, M - j0);
    int ntile = (jrows + 15) >> 4;
    for (int jt = 0; jt < ntile; ++jt) {
        int gtj = sg[jt * 16 + r];
        bf16x8 bh = *(const bf16x8*)(sc_hi + (jt * 16 + r) * 40 + quad * 8);
        bf16x8 bl = *(const bf16x8*)(sc_lo + (jt * 16 + r) * 40 + quad * 8);
        bool jv = (gtj >= 0);
        #pragma unroll
        for (int it = 0; it < 2; ++it) {
            f32x4 acc = {0.f, 0.f, 0.f, 0.f};
            acc = __builtin_amdgcn_mfma_f32_16x16x32_bf16(a_hi[it], bh, acc, 0, 0, 0);
            acc = __builtin_amdgcn_mfma_f32_16x16x32_bf16(a_hi[it], bl, acc, 0, 0, 0);
            acc = __builtin_amdgcn_mfma_f32_16x16x32_bf16(a_lo[it], bh, acc, 0, 0, 0);
            #pragma unroll
            for (int r4 = 0; r4 < 4; ++r4) {
                float s = acc[r4];
                bool same = (gtj == gt_i[it][r4]);
                float sm = (same || !jv) ? -INFINITY : s;
                best[it][r4] = fmaxf(best[it][r4], sm);
                cnt[it][r4] += same ? 1 : 0;   // self-pair included; fixed in combine
            }
        }
    }

    #pragma unroll
    for (int it = 0; it < 2; ++it) {
        #pragma unroll
        for (int r4 = 0; r4 < 4; ++r4) {
            float bb = best[it][r4];
            int cc = cnt[it][r4];
            #pragma unroll
            for (int mk = 1; mk < 16; mk <<= 1) {
                bb = fmaxf(bb, __shfl_xor(bb, mk));
                cc += __shfl_xor(cc, mk);
            }
            if (r == 0) {
                int ia = ib + it * 16 + quad * 4 + r4;
                if (ia < M) {
                    p_cnt[((size_t)b * N_ + ia) * NCHJ + blockIdx.y] = (unsigned short)cc;
                    if (bb > -INFINITY) atomicMax(&bestArr[b * N_ + ia], fmap(bb));
                }
            }
        }
    }
}

// ---------------- Kernel 3: combine — one wave per anchor, NO global atomics ----------------
// Lane 0 writes (contrib, flag) to per-anchor arrays; k_final reduces them.
__global__ __launch_bounds__(256) void k_combine(const unsigned short* __restrict__ hi_g,
                                                 const unsigned short* __restrict__ lo_g,
                                                 const int* __restrict__ cg,
                                                 const int* __restrict__ clist,
                                                 const int* __restrict__ Marr,
                                                 const float* __restrict__ pos_rand,
                                                 const unsigned short* __restrict__ p_cnt,
                                                 const unsigned* __restrict__ bestArr,
                                                 float* __restrict__ cArr,
                                                 int* __restrict__ vArr) {
    int b = blockIdx.y;
    int M = Marr[b];
    int t = threadIdx.x;
    int w = t >> 6, lane = t & 63;
    int i = blockIdx.x * 4 + w;           // this wave's anchor (wave-uniform)

    if (i >= M) return;                    // wave-uniform

    float contrib = 0.0f;
    int vflag = 0;

    int nchj = (M + TJ - 1) / TJ;
    int ich = i / TJ;
    const unsigned short* pc = p_cnt + ((size_t)b * N_ + i) * NCHJ;
    int c_s = 0;
    if (lane < nchj) c_s = (int)pc[lane] - (lane == ich ? 1 : 0);  // self removed
    // inclusive 64-lane scan
    int P = c_s;
    #pragma unroll
    for (int off = 1; off < 64; off <<= 1) {
        int n = __shfl_up(P, off);
        if (lane >= off) P += n;
    }
    int num_pos = __shfl(P, 63);
    unsigned bu = bestArr[b * N_ + i];
    if (num_pos >= 1 && bu != NEG_INF_MAPPED) {   // wave-uniform
        float best = funmap(bu);
        int orig = clist[b * N_ + i];
        float u = pos_rand[b * N_ + orig];
        int pcx = (int)floorf(u * (float)num_pos);   // matches jnp f32 math
        int hi2 = num_pos - 1;
        pcx = pcx < 0 ? 0 : (pcx > hi2 ? hi2 : pcx);
        int target = pcx + 1;
        // first chunk where inclusive prefix reaches target
        unsigned long long selm = __ballot(P >= target);
        int sstar = __ffsll((unsigned long long)selm) - 1;
        int c0 = (sstar > 0) ? __shfl(P, sstar - 1) : 0;
        int need = target - c0;       // wave-uniform, >= 1
        int jstart = sstar * TJ;
        int jend = min(jstart + TJ, M);
        int ga = cg[b * N_ + i];
        int posj = -1;
        #pragma unroll
        for (int k = 0; k < 4; ++k) {
            if (posj >= 0) continue;
            int j = jstart + k * 64 + lane;
            bool flag = (j < jend) && (cg[b * N_ + j] == ga) && (j != i);
            unsigned long long mk = __ballot(flag);
            int tot = __popcll(mk);
            if (need <= tot) {
                int pfx = __popcll(mk & ((1ull << lane) - 1ull));
                unsigned long long sel = __ballot(flag && (pfx == need - 1));
                posj = jstart + k * 64 + (__ffsll((unsigned long long)sel) - 1);
            } else {
                need -= tot;
            }
        }
        // lane-parallel dot over the 16 packed-bf16 pairs (fp32 reconstruct)
        float part = 0.0f;
        if (lane < 16) {
            unsigned xh = ((const unsigned*)(hi_g + ((size_t)b * N_ + i) * 32))[lane];
            unsigned xl = ((const unsigned*)(lo_g + ((size_t)b * N_ + i) * 32))[lane];
            unsigned yh = ((const unsigned*)(hi_g + ((size_t)b * N_ + posj) * 32))[lane];
            unsigned yl = ((const unsigned*)(lo_g + ((size_t)b * N_ + posj) * 32))[lane];
            float a0, a1, b0, b1, c0f, c1f, d0, d1;
            bf2x(xh, a0, a1); bf2x(xl, b0, b1);
            bf2x(yh, c0f, c1f); bf2x(yl, d0, d1);
            part = fmaf(a0 + b0, c0f + d0, (a1 + b1) * (c1f + d1));
        }
        #pragma unroll
        for (int mk2 = 1; mk2 < 16; mk2 <<= 1) part += __shfl_xor(part, mk2);
        float dot = part;
        float pos_d = sqrtf(fmaxf(2.f - 2.f * dot, 0.f) + 1e-12f);
        float neg_d = sqrtf(fmaxf(2.f - 2.f * best, 0.f) + 1e-12f);
        contrib = fmaxf(pos_d - neg_d + MARGIN_, 0.0f);
        vflag = 1;
    }

    if (lane == 0) {
        cArr[b * N_ + i] = contrib;
        vArr[b * N_ + i] = vflag;
    }
}

// ---------------- Kernel 4: final reduction (single block) ----------------
__global__ __launch_bounds__(1024) void k_final(const float* __restrict__ cArr,
                                                const int* __restrict__ vArr,
                                                const int* __restrict__ Marr,
                                                float* __restrict__ out) {
    int tid = threadIdx.x;
    float tv = 0.0f;
    int tc = 0;
    #pragma unroll
    for (int b = 0; b < B_; ++b) {
        int M = Marr[b];
        for (int i = tid; i < M; i += 1024) {
            tv += cArr[b * N_ + i];
            tc += vArr[b * N_ + i];
        }
    }
    #pragma unroll
    for (int off = 32; off > 0; off >>= 1) {
        tv += __shfl_down(tv, off);
        tc += __shfl_down(tc, off);
    }
    __shared__ float sv[16];
    __shared__ int scnt[16];
    int lane = tid & 63, w = tid >> 6;
    if (lane == 0) { sv[w] = tv; scnt[w] = tc; }
    __syncthreads();
    if (tid == 0) {
        float T = 0.0f; int C = 0;
        #pragma unroll
        for (int k = 0; k < 16; ++k) { T += sv[k]; C += scnt[k]; }
        out[0] = (C > 0) ? (T / (float)C) : 0.0f;
    }
}

// ---------------- launch ----------------
extern "C" void kernel_launch(void* const* d_in, const int* in_sizes, int n_in,
                              void* d_out, int out_size, void* d_ws, size_t ws_size,
                              hipStream_t stream) {
    const float* pred     = (const float*)d_in[0];
    const float* pos_rand = (const float*)d_in[1];
    const int*   gt       = (const int*)d_in[2];
    const int*   fg       = (const int*)d_in[3];
    float* out = (float*)d_out;

    char* ws = (char*)d_ws;
    // layout (bytes):
    //   hi_g     : 0         .. 1,638,400   (B*N*32 bf16)
    //   lo_g     : 1,638,400 .. 3,276,800
    //   clist    : 3,276,800 .. 3,379,200   (B*N i32)
    //   cg       : 3,379,200 .. 3,481,600   (B*N i32)
    //   Marr     : 3,481,600 .. 3,481,664
    //   bestArr  : 3,482,688 .. 3,585,088   (B*N u32)
    //   p_cnt    : 3,585,088 .. 4,865,088   (B*N*NCHJ u16)
    //   cArr     : 4,865,088 .. 4,967,488   (B*N f32)
    //   vArr     : 4,967,488 .. 5,069,888   (B*N i32)
    unsigned short* hi_g    = (unsigned short*)(ws);
    unsigned short* lo_g    = (unsigned short*)(ws + 1638400);
    int*            clist   = (int*)(ws + 3276800);
    int*            cg      = (int*)(ws + 3379200);
    int*            Marr    = (int*)(ws + 3481600);
    unsigned*       bestArr = (unsigned*)(ws + 3482688);
    unsigned short* p_cnt   = (unsigned short*)(ws + 3585088);
    float*          cArr    = (float*)(ws + 4865088);
    int*            vArr    = (int*)(ws + 4967488);

    k_compact<<<B_, 1024, 0, stream>>>(pred, gt, fg, hi_g, lo_g, clist, cg, Marr, bestArr);
    dim3 gp((N_ + TI - 1) / TI, (N_ + TJ - 1) / TJ, B_);
    k_pass<<<gp, 256, 0, stream>>>(hi_g, lo_g, cg, Marr, p_cnt, bestArr);
    dim3 gc((N_ + 3) / 4, B_);
    k_combine<<<gc, 256, 0, stream>>>(hi_g, lo_g, cg, clist, Marr, pos_rand, p_cnt, bestArr, cArr, vArr);
    k_final<<<1, 1024, 0, stream>>>(cArr, vArr, Marr, out);
}

// Round 6
// 105.683 us; speedup vs baseline: 2.1440x; 1.4786x over previous
//
#include <hip/hip_runtime.h>
#include <math.h>

// Problem constants (fixed by the reference setup)
#define B_ 4
#define N_ 6400
#define D_ 32
#define TJ 256          // j-chunk staged in LDS (k_pass), also combine chunking
#define NCHJ 25         // N_/TJ
#define TI 128          // anchors per k_pass block (4 waves x 2 i-tiles x 16)
#define CHUNK 256       // compaction chunk
#define NCC 25          // N_/CHUNK

typedef __attribute__((ext_vector_type(4))) float f32x4;
typedef __attribute__((ext_vector_type(8))) short bf16x8;

static constexpr float MARGIN_ = 0.3f;

// monotone float<->uint map so atomicMax(uint) == float max
__device__ __forceinline__ unsigned fmap(float f) {
    unsigned u = __float_as_uint(f);
    return (u & 0x80000000u) ? ~u : (u | 0x80000000u);
}
__device__ __forceinline__ float funmap(unsigned u) {
    return (u & 0x80000000u) ? __uint_as_float(u ^ 0x80000000u)
                             : __uint_as_float(~u);
}
#define NEG_INF_MAPPED 0x007FFFFFu   // fmap(-inf)

// round-to-nearest-even f32 -> bf16
__device__ __forceinline__ unsigned short f2bf(float f) {
    unsigned u = __float_as_uint(f);
    unsigned r = u + 0x7fffu + ((u >> 16) & 1u);
    return (unsigned short)(r >> 16);
}
__device__ __forceinline__ float bf2f(unsigned short h) {
    return __uint_as_float(((unsigned)h) << 16);
}
// unpack packed bf16 pair (elem even in low 16, odd in high 16)
__device__ __forceinline__ void bf2x(unsigned u, float& e0, float& e1) {
    e0 = __uint_as_float(u << 16);
    e1 = __uint_as_float(u & 0xffff0000u);
}

// ---------------- Kernel 1: per-chunk fg counts + bestArr init ----------------
__global__ __launch_bounds__(256) void k_count(const int* __restrict__ fg,
                                               int* __restrict__ chunkcnt,
                                               unsigned* __restrict__ bestArr) {
    int c = blockIdx.x, b = blockIdx.y;
    int t = threadIdx.x;
    int idx = c * CHUNK + t;
    bestArr[b * N_ + idx] = NEG_INF_MAPPED;
    bool flag = fg[b * N_ + idx] != 0;
    unsigned long long m = __ballot(flag);
    __shared__ int wsh[4];
    if ((t & 63) == 0) wsh[t >> 6] = __popcll(m);
    __syncthreads();
    if (t == 0) chunkcnt[b * NCC + c] = wsh[0] + wsh[1] + wsh[2] + wsh[3];
}

// ---------------- Kernel 2: scatter (prefix computed in-kernel) ----------------
// Wave 0 shuffle-scans the 25 chunk counts -> this block's base offset + M.
// Then ballot-rank within the chunk, scatter clist/cg, gather + normalize +
// bf16 hi/lo split (1 row per flagged thread). Block c==0 writes Marr[b].
__global__ __launch_bounds__(256) void k_scatter(const float* __restrict__ pred,
                                                 const int* __restrict__ gt,
                                                 const int* __restrict__ fg,
                                                 const int* __restrict__ chunkcnt,
                                                 unsigned short* __restrict__ hi_g,
                                                 unsigned short* __restrict__ lo_g,
                                                 int* __restrict__ clist,
                                                 int* __restrict__ cg,
                                                 int* __restrict__ Marr) {
    int c = blockIdx.x, b = blockIdx.y;
    int t = threadIdx.x;
    int lane = t & 63, w = t >> 6;

    __shared__ int s_off, s_M;
    if (w == 0) {
        int v = (lane < NCC) ? chunkcnt[b * NCC + lane] : 0;
        int P = v;
        #pragma unroll
        for (int off = 1; off < 32; off <<= 1) {
            int n = __shfl_up(P, off);
            if (lane >= off) P += n;
        }
        int offc = __shfl(P, (c > 0) ? (c - 1) : 0);
        if (c == 0) offc = 0;
        int Mtot = __shfl(P, NCC - 1);
        if (lane == 0) { s_off = offc; s_M = Mtot; }
    }
    __syncthreads();
    if (c == 0 && t == 0) Marr[b] = s_M;

    int idx = c * CHUNK + t;
    bool flag = fg[b * N_ + idx] != 0;
    unsigned long long m = __ballot(flag);
    int lp = __popcll(m & ((1ull << lane) - 1ull));
    __shared__ int wsh[4];
    if (lane == 0) wsh[w] = __popcll(m);
    __syncthreads();
    int woff = 0;
    #pragma unroll
    for (int k = 0; k < 4; ++k) if (k < w) woff += wsh[k];
    if (!flag) return;

    int rank = s_off + woff + lp;
    clist[b * N_ + rank] = idx;
    cg[b * N_ + rank] = gt[b * N_ + idx];

    const float4* s4 = (const float4*)(pred + ((size_t)b * N_ + idx) * D_);
    float f[32];
    float ssq = 0.0f;
    #pragma unroll
    for (int k = 0; k < 8; ++k) {
        float4 q = s4[k];
        f[k * 4] = q.x; f[k * 4 + 1] = q.y; f[k * 4 + 2] = q.z; f[k * 4 + 3] = q.w;
        ssq += q.x * q.x + q.y * q.y + q.z * q.z + q.w * q.w;
    }
    float inv = 1.0f / fmaxf(sqrtf(ssq), 1e-12f);
    unsigned hw[16], lw[16];
    #pragma unroll
    for (int k = 0; k < 16; ++k) {
        float x0 = f[2 * k] * inv, x1 = f[2 * k + 1] * inv;
        unsigned short h0 = f2bf(x0), h1 = f2bf(x1);
        unsigned short l0 = f2bf(x0 - bf2f(h0)), l1 = f2bf(x1 - bf2f(h1));
        hw[k] = (unsigned)h0 | ((unsigned)h1 << 16);
        lw[k] = (unsigned)l0 | ((unsigned)l1 << 16);
    }
    uint4* dh = (uint4*)(hi_g + ((size_t)b * N_ + rank) * 32);
    uint4* dl = (uint4*)(lo_g + ((size_t)b * N_ + rank) * 32);
    #pragma unroll
    for (int k = 0; k < 4; ++k) {
        dh[k] = make_uint4(hw[4 * k], hw[4 * k + 1], hw[4 * k + 2], hw[4 * k + 3]);
        dl[k] = make_uint4(lw[4 * k], lw[4 * k + 1], lw[4 * k + 2], lw[4 * k + 3]);
    }
}

// ---------------- Kernel 3: MFMA pair pass (verified since R3) ----------------
// grid = (ceil(N/TI), ceil(N/TJ), B). Wave covers 2 i-tiles of 16 anchors.
// S-tile = 16x16 via mfma_f32_16x16x32_bf16, 3 terms (hi*hi + hi*lo + lo*hi).
// C/D layout: col = lane&15, row = (lane>>4)*4 + reg  [m89-verified].
__global__ __launch_bounds__(256) void k_pass(const unsigned short* __restrict__ hi_g,
                                              const unsigned short* __restrict__ lo_g,
                                              const int* __restrict__ cg,
                                              const int* __restrict__ Marr,
                                              unsigned short* __restrict__ p_cnt,
                                              unsigned* __restrict__ bestArr) {
    int b = blockIdx.z;
    int M = Marr[b];
    int i0 = blockIdx.x * TI;
    int j0 = blockIdx.y * TJ;
    if (i0 >= M || j0 >= M) return;   // block-uniform exit

    // LDS rows padded to 80 B (40 shorts): 16-lane frag reads = 2-way banks (free)
    __shared__ __align__(16) unsigned short sc_hi[TJ * 40];  // 20 KB
    __shared__ __align__(16) unsigned short sc_lo[TJ * 40];  // 20 KB
    __shared__ int sg[TJ];
    int t = threadIdx.x;

    {
        int j = j0 + t;
        sg[t] = (j < M) ? cg[b * N_ + j] : -1;
    }
    {   // stage: thread -> (row = p*64 + t>>2, 16B seg = t&3); coalesced global reads
        int seg = t & 3, r0 = t >> 2;
        #pragma unroll
        for (int p = 0; p < 4; ++p) {
            int row = p * 64 + r0;
            int j = j0 + row;
            uint4 vh = make_uint4(0u, 0u, 0u, 0u), vl = make_uint4(0u, 0u, 0u, 0u);
            if (j < M) {
                vh = *(const uint4*)(hi_g + ((size_t)b * N_ + j) * 32 + seg * 8);
                vl = *(const uint4*)(lo_g + ((size_t)b * N_ + j) * 32 + seg * 8);
            }
            *(uint4*)(sc_hi + row * 40 + seg * 8) = vh;
            *(uint4*)(sc_lo + row * 40 + seg * 8) = vl;
        }
    }
    __syncthreads();

    int lane = t & 63, w = t >> 6;
    int r = lane & 15, quad = lane >> 4;
    int ib = i0 + w * 32;            // this wave's 32 anchors (2 i-tiles)

    bf16x8 a_hi[2], a_lo[2];
    int gt_i[2][4];
    #pragma unroll
    for (int it = 0; it < 2; ++it) {
        int i = ib + it * 16 + r;
        bf16x8 zh = {0, 0, 0, 0, 0, 0, 0, 0};
        a_hi[it] = zh; a_lo[it] = zh;
        if (i < M) {
            a_hi[it] = *(const bf16x8*)(hi_g + ((size_t)b * N_ + i) * 32 + quad * 8);
            a_lo[it] = *(const bf16x8*)(lo_g + ((size_t)b * N_ + i) * 32 + quad * 8);
        }
        #pragma unroll
        for (int r4 = 0; r4 < 4; ++r4) {
            int ia = ib + it * 16 + quad * 4 + r4;
            gt_i[it][r4] = (ia < M) ? cg[b * N_ + ia] : -2;
        }
    }

    float best[2][4];
    int cnt[2][4];
    #pragma unroll
    for (int it = 0; it < 2; ++it)
        #pragma unroll
        for (int r4 = 0; r4 < 4; ++r4) { best[it][r4] = -INFINITY; cnt[it][r4] = 0; }

    int jrows = min(TJ, M - j0);
    int ntile = (jrows + 15) >> 4;
    for (int jt = 0; jt < ntile; ++jt) {
        int gtj = sg[jt * 16 + r];
        bf16x8 bh = *(const bf16x8*)(sc_hi + (jt * 16 + r) * 40 + quad * 8);
        bf16x8 bl = *(const bf16x8*)(sc_lo + (jt * 16 + r) * 40 + quad * 8);
        bool jv = (gtj >= 0);
        #pragma unroll
        for (int it = 0; it < 2; ++it) {
            f32x4 acc = {0.f, 0.f, 0.f, 0.f};
            acc = __builtin_amdgcn_mfma_f32_16x16x32_bf16(a_hi[it], bh, acc, 0, 0, 0);
            acc = __builtin_amdgcn_mfma_f32_16x16x32_bf16(a_hi[it], bl, acc, 0, 0, 0);
            acc = __builtin_amdgcn_mfma_f32_16x16x32_bf16(a_lo[it], bh, acc, 0, 0, 0);
            #pragma unroll
            for (int r4 = 0; r4 < 4; ++r4) {
                float s = acc[r4];
                bool same = (gtj == gt_i[it][r4]);
                float sm = (same || !jv) ? -INFINITY : s;
                best[it][r4] = fmaxf(best[it][r4], sm);
                cnt[it][r4] += same ? 1 : 0;   // self-pair included; fixed in combine
            }
        }
    }

    #pragma unroll
    for (int it = 0; it < 2; ++it) {
        #pragma unroll
        for (int r4 = 0; r4 < 4; ++r4) {
            float bb = best[it][r4];
            int cc = cnt[it][r4];
            #pragma unroll
            for (int mk = 1; mk < 16; mk <<= 1) {
                bb = fmaxf(bb, __shfl_xor(bb, mk));
                cc += __shfl_xor(cc, mk);
            }
            if (r == 0) {
                int ia = ib + it * 16 + quad * 4 + r4;
                if (ia < M) {
                    p_cnt[((size_t)b * N_ + ia) * NCHJ + blockIdx.y] = (unsigned short)cc;
                    if (bb > -INFINITY) atomicMax(&bestArr[b * N_ + ia], fmap(bb));
                }
            }
        }
    }
}

// ---------------- Kernel 4: combine — one wave per anchor, no global atomics ----------------
__global__ __launch_bounds__(256) void k_combine(const unsigned short* __restrict__ hi_g,
                                                 const unsigned short* __restrict__ lo_g,
                                                 const int* __restrict__ cg,
                                                 const int* __restrict__ clist,
                                                 const int* __restrict__ Marr,
                                                 const float* __restrict__ pos_rand,
                                                 const unsigned short* __restrict__ p_cnt,
                                                 const unsigned* __restrict__ bestArr,
                                                 float* __restrict__ cArr,
                                                 int* __restrict__ vArr) {
    int b = blockIdx.y;
    int M = Marr[b];
    int t = threadIdx.x;
    int w = t >> 6, lane = t & 63;
    int i = blockIdx.x * 4 + w;           // this wave's anchor (wave-uniform)

    if (i >= M) return;                    // wave-uniform

    float contrib = 0.0f;
    int vflag = 0;

    int nchj = (M + TJ - 1) / TJ;
    int ich = i / TJ;
    const unsigned short* pc = p_cnt + ((size_t)b * N_ + i) * NCHJ;
    int c_s = 0;
    if (lane < nchj) c_s = (int)pc[lane] - (lane == ich ? 1 : 0);  // self removed
    // inclusive 64-lane scan
    int P = c_s;
    #pragma unroll
    for (int off = 1; off < 64; off <<= 1) {
        int n = __shfl_up(P, off);
        if (lane >= off) P += n;
    }
    int num_pos = __shfl(P, 63);
    unsigned bu = bestArr[b * N_ + i];
    if (num_pos >= 1 && bu != NEG_INF_MAPPED) {   // wave-uniform
        float best = funmap(bu);
        int orig = clist[b * N_ + i];
        float u = pos_rand[b * N_ + orig];
        int pcx = (int)floorf(u * (float)num_pos);   // matches jnp f32 math
        int hi2 = num_pos - 1;
        pcx = pcx < 0 ? 0 : (pcx > hi2 ? hi2 : pcx);
        int target = pcx + 1;
        // first chunk where inclusive prefix reaches target
        unsigned long long selm = __ballot(P >= target);
        int sstar = __ffsll((unsigned long long)selm) - 1;
        int c0 = (sstar > 0) ? __shfl(P, sstar - 1) : 0;
        int need = target - c0;       // wave-uniform, >= 1
        int jstart = sstar * TJ;
        int jend = min(jstart + TJ, M);
        int ga = cg[b * N_ + i];
        int posj = -1;
        #pragma unroll
        for (int k = 0; k < 4; ++k) {
            if (posj >= 0) continue;
            int j = jstart + k * 64 + lane;
            bool flag = (j < jend) && (cg[b * N_ + j] == ga) && (j != i);
            unsigned long long mk = __ballot(flag);
            int tot = __popcll(mk);
            if (need <= tot) {
                int pfx = __popcll(mk & ((1ull << lane) - 1ull));
                unsigned long long sel = __ballot(flag && (pfx == need - 1));
                posj = jstart + k * 64 + (__ffsll((unsigned long long)sel) - 1);
            } else {
                need -= tot;
            }
        }
        // lane-parallel dot over the 16 packed-bf16 pairs (fp32 reconstruct)
        float part = 0.0f;
        if (lane < 16) {
            unsigned xh = ((const unsigned*)(hi_g + ((size_t)b * N_ + i) * 32))[lane];
            unsigned xl = ((const unsigned*)(lo_g + ((size_t)b * N_ + i) * 32))[lane];
            unsigned yh = ((const unsigned*)(hi_g + ((size_t)b * N_ + posj) * 32))[lane];
            unsigned yl = ((const unsigned*)(lo_g + ((size_t)b * N_ + posj) * 32))[lane];
            float a0, a1, b0, b1, c0f, c1f, d0, d1;
            bf2x(xh, a0, a1); bf2x(xl, b0, b1);
            bf2x(yh, c0f, c1f); bf2x(yl, d0, d1);
            part = fmaf(a0 + b0, c0f + d0, (a1 + b1) * (c1f + d1));
        }
        #pragma unroll
        for (int mk2 = 1; mk2 < 16; mk2 <<= 1) part += __shfl_xor(part, mk2);
        float dot = part;
        float pos_d = sqrtf(fmaxf(2.f - 2.f * dot, 0.f) + 1e-12f);
        float neg_d = sqrtf(fmaxf(2.f - 2.f * best, 0.f) + 1e-12f);
        contrib = fmaxf(pos_d - neg_d + MARGIN_, 0.0f);
        vflag = 1;
    }

    if (lane == 0) {
        cArr[b * N_ + i] = contrib;
        vArr[b * N_ + i] = vflag;
    }
}

// ---------------- Kernel 5: final reduction (single block) ----------------
__global__ __launch_bounds__(1024) void k_final(const float* __restrict__ cArr,
                                                const int* __restrict__ vArr,
                                                const int* __restrict__ Marr,
                                                float* __restrict__ out) {
    int tid = threadIdx.x;
    float tv = 0.0f;
    int tc = 0;
    #pragma unroll
    for (int b = 0; b < B_; ++b) {
        int M = Marr[b];
        for (int i = tid; i < M; i += 1024) {
            tv += cArr[b * N_ + i];
            tc += vArr[b * N_ + i];
        }
    }
    #pragma unroll
    for (int off = 32; off > 0; off >>= 1) {
        tv += __shfl_down(tv, off);
        tc += __shfl_down(tc, off);
    }
    __shared__ float sv[16];
    __shared__ int scnt[16];
    int lane = tid & 63, w = tid >> 6;
    if (lane == 0) { sv[w] = tv; scnt[w] = tc; }
    __syncthreads();
    if (tid == 0) {
        float T = 0.0f; int C = 0;
        #pragma unroll
        for (int k = 0; k < 16; ++k) { T += sv[k]; C += scnt[k]; }
        out[0] = (C > 0) ? (T / (float)C) : 0.0f;
    }
}

// ---------------- launch ----------------
extern "C" void kernel_launch(void* const* d_in, const int* in_sizes, int n_in,
                              void* d_out, int out_size, void* d_ws, size_t ws_size,
                              hipStream_t stream) {
    const float* pred     = (const float*)d_in[0];
    const float* pos_rand = (const float*)d_in[1];
    const int*   gt       = (const int*)d_in[2];
    const int*   fg       = (const int*)d_in[3];
    float* out = (float*)d_out;

    char* ws = (char*)d_ws;
    // layout (bytes):
    //   hi_g     : 0         .. 1,638,400   (B*N*32 bf16)
    //   lo_g     : 1,638,400 .. 3,276,800
    //   clist    : 3,276,800 .. 3,379,200   (B*N i32)
    //   cg       : 3,379,200 .. 3,481,600   (B*N i32)
    //   Marr     : 3,481,600 .. 3,481,664
    //   chunkcnt : 3,481,664 .. 3,482,064   (B*NCC i32)
    //   bestArr  : 3,482,688 .. 3,585,088   (B*N u32)
    //   p_cnt    : 3,585,088 .. 4,865,088   (B*N*NCHJ u16)
    //   cArr     : 4,865,088 .. 4,967,488   (B*N f32)
    //   vArr     : 4,967,488 .. 5,069,888   (B*N i32)
    unsigned short* hi_g    = (unsigned short*)(ws);
    unsigned short* lo_g    = (unsigned short*)(ws + 1638400);
    int*            clist   = (int*)(ws + 3276800);
    int*            cg      = (int*)(ws + 3379200);
    int*            Marr    = (int*)(ws + 3481600);
    int*            chunkcnt= (int*)(ws + 3481664);
    unsigned*       bestArr = (unsigned*)(ws + 3482688);
    unsigned short* p_cnt   = (unsigned short*)(ws + 3585088);
    float*          cArr    = (float*)(ws + 4865088);
    int*            vArr    = (int*)(ws + 4967488);

    dim3 gcb(NCC, B_);
    k_count<<<gcb, 256, 0, stream>>>(fg, chunkcnt, bestArr);
    k_scatter<<<gcb, 256, 0, stream>>>(pred, gt, fg, chunkcnt, hi_g, lo_g, clist, cg, Marr);
    dim3 gp((N_ + TI - 1) / TI, (N_ + TJ - 1) / TJ, B_);
    k_pass<<<gp, 256, 0, stream>>>(hi_g, lo_g, cg, Marr, p_cnt, bestArr);
    dim3 gc((N_ + 3) / 4, B_);
    k_combine<<<gc, 256, 0, stream>>>(hi_g, lo_g, cg, clist, Marr, pos_rand, p_cnt, bestArr, cArr, vArr);
    k_final<<<1, 1024, 0, stream>>>(cArr, vArr, Marr, out);
}

// Round 7
// 103.578 us; speedup vs baseline: 2.1876x; 1.0203x over previous
//
#include <hip/hip_runtime.h>
#include <math.h>

// Problem constants (fixed by the reference setup)
#define B_ 4
#define N_ 6400
#define D_ 32
#define TJ 256          // j-chunk staged in LDS (k_pass), also combine chunking
#define NCHJ 25         // N_/TJ
#define TI 128          // anchors per k_pass block (4 waves x 2 i-tiles x 16)
#define CHUNK 256       // compaction chunk
#define NCC 25          // N_/CHUNK

typedef __attribute__((ext_vector_type(4))) float f32x4;
typedef __attribute__((ext_vector_type(8))) short bf16x8;

static constexpr float MARGIN_ = 0.3f;

// monotone float<->uint map so atomicMax(uint) == float max
__device__ __forceinline__ unsigned fmap(float f) {
    unsigned u = __float_as_uint(f);
    return (u & 0x80000000u) ? ~u : (u | 0x80000000u);
}
__device__ __forceinline__ float funmap(unsigned u) {
    return (u & 0x80000000u) ? __uint_as_float(u ^ 0x80000000u)
                             : __uint_as_float(~u);
}
#define NEG_INF_MAPPED 0x007FFFFFu   // fmap(-inf)

// round-to-nearest-even f32 -> bf16
__device__ __forceinline__ unsigned short f2bf(float f) {
    unsigned u = __float_as_uint(f);
    unsigned r = u + 0x7fffu + ((u >> 16) & 1u);
    return (unsigned short)(r >> 16);
}
__device__ __forceinline__ float bf2f(unsigned short h) {
    return __uint_as_float(((unsigned)h) << 16);
}
// unpack packed bf16 pair (elem even in low 16, odd in high 16)
__device__ __forceinline__ void bf2x(unsigned u, float& e0, float& e1) {
    e0 = __uint_as_float(u << 16);
    e1 = __uint_as_float(u & 0xffff0000u);
}

// ---------------- Kernel 1: self-contained prep ----------------
// grid (25, B). Wave 0 re-derives all 25 chunk fg-counts from fg (25 coalesced
// int4 loads + shuffle reduce) -> this block's prefix offset + M, no separate
// count kernel, no extra dependency. Then ballot-rank, scatter clist/cg,
// gather + normalize + bf16 hi/lo split. Also inits bestArr. Block c==0
// writes Marr[b].
__global__ __launch_bounds__(256) void k_prep(const float* __restrict__ pred,
                                              const int* __restrict__ gt,
                                              const int* __restrict__ fg,
                                              unsigned short* __restrict__ hi_g,
                                              unsigned short* __restrict__ lo_g,
                                              int* __restrict__ clist,
                                              int* __restrict__ cg,
                                              int* __restrict__ Marr,
                                              unsigned* __restrict__ bestArr) {
    int c = blockIdx.x, b = blockIdx.y;
    int t = threadIdx.x;
    int lane = t & 63, w = t >> 6;
    int idx = c * CHUNK + t;

    bestArr[b * N_ + idx] = NEG_INF_MAPPED;

    // own-chunk ballot rank
    bool flag = fg[b * N_ + idx] != 0;
    unsigned long long m = __ballot(flag);
    int lp = __popcll(m & ((1ull << lane) - 1ull));
    __shared__ int wsh[4];
    __shared__ int s_off, s_M;
    if (lane == 0) wsh[w] = __popcll(m);

    // wave 0: scan all 25 chunk counts of this batch (independent int4 loads)
    if (w == 0) {
        int pre = 0, tot = 0;
        #pragma unroll
        for (int cc = 0; cc < NCC; ++cc) {
            const int4 v = ((const int4*)(fg + (size_t)b * N_ + cc * CHUNK))[lane];
            int cnt = (v.x != 0) + (v.y != 0) + (v.z != 0) + (v.w != 0);
            #pragma unroll
            for (int o = 1; o < 64; o <<= 1) cnt += __shfl_xor(cnt, o);
            pre += (cc < c) ? cnt : 0;
            tot += cnt;
        }
        if (lane == 0) { s_off = pre; s_M = tot; }
    }
    __syncthreads();
    if (c == 0 && t == 0) Marr[b] = s_M;
    if (!flag) return;

    int woff = 0;
    #pragma unroll
    for (int k = 0; k < 4; ++k) if (k < w) woff += wsh[k];
    int rank = s_off + woff + lp;
    clist[b * N_ + rank] = idx;
    cg[b * N_ + rank] = gt[b * N_ + idx];

    const float4* s4 = (const float4*)(pred + ((size_t)b * N_ + idx) * D_);
    float f[32];
    float ssq = 0.0f;
    #pragma unroll
    for (int k = 0; k < 8; ++k) {
        float4 q = s4[k];
        f[k * 4] = q.x; f[k * 4 + 1] = q.y; f[k * 4 + 2] = q.z; f[k * 4 + 3] = q.w;
        ssq += q.x * q.x + q.y * q.y + q.z * q.z + q.w * q.w;
    }
    float inv = 1.0f / fmaxf(sqrtf(ssq), 1e-12f);
    unsigned hw[16], lw[16];
    #pragma unroll
    for (int k = 0; k < 16; ++k) {
        float x0 = f[2 * k] * inv, x1 = f[2 * k + 1] * inv;
        unsigned short h0 = f2bf(x0), h1 = f2bf(x1);
        unsigned short l0 = f2bf(x0 - bf2f(h0)), l1 = f2bf(x1 - bf2f(h1));
        hw[k] = (unsigned)h0 | ((unsigned)h1 << 16);
        lw[k] = (unsigned)l0 | ((unsigned)l1 << 16);
    }
    uint4* dh = (uint4*)(hi_g + ((size_t)b * N_ + rank) * 32);
    uint4* dl = (uint4*)(lo_g + ((size_t)b * N_ + rank) * 32);
    #pragma unroll
    for (int k = 0; k < 4; ++k) {
        dh[k] = make_uint4(hw[4 * k], hw[4 * k + 1], hw[4 * k + 2], hw[4 * k + 3]);
        dl[k] = make_uint4(lw[4 * k], lw[4 * k + 1], lw[4 * k + 2], lw[4 * k + 3]);
    }
}

// ---------------- Kernel 2: MFMA pair pass (verified since R3) ----------------
// grid = (ceil(N/TI), ceil(N/TJ), B). Wave covers 2 i-tiles of 16 anchors.
// S-tile = 16x16 via mfma_f32_16x16x32_bf16, 3 terms (hi*hi + hi*lo + lo*hi).
// C/D layout: col = lane&15, row = (lane>>4)*4 + reg  [m89-verified].
__global__ __launch_bounds__(256) void k_pass(const unsigned short* __restrict__ hi_g,
                                              const unsigned short* __restrict__ lo_g,
                                              const int* __restrict__ cg,
                                              const int* __restrict__ Marr,
                                              unsigned short* __restrict__ p_cnt,
                                              unsigned* __restrict__ bestArr) {
    int b = blockIdx.z;
    int M = Marr[b];
    int i0 = blockIdx.x * TI;
    int j0 = blockIdx.y * TJ;
    if (i0 >= M || j0 >= M) return;   // block-uniform exit

    // LDS rows padded to 80 B (40 shorts): 16-lane frag reads = 2-way banks (free)
    __shared__ __align__(16) unsigned short sc_hi[TJ * 40];  // 20 KB
    __shared__ __align__(16) unsigned short sc_lo[TJ * 40];  // 20 KB
    __shared__ int sg[TJ];
    int t = threadIdx.x;

    {
        int j = j0 + t;
        sg[t] = (j < M) ? cg[b * N_ + j] : -1;
    }
    {   // stage: thread -> (row = p*64 + t>>2, 16B seg = t&3); coalesced global reads
        int seg = t & 3, r0 = t >> 2;
        #pragma unroll
        for (int p = 0; p < 4; ++p) {
            int row = p * 64 + r0;
            int j = j0 + row;
            uint4 vh = make_uint4(0u, 0u, 0u, 0u), vl = make_uint4(0u, 0u, 0u, 0u);
            if (j < M) {
                vh = *(const uint4*)(hi_g + ((size_t)b * N_ + j) * 32 + seg * 8);
                vl = *(const uint4*)(lo_g + ((size_t)b * N_ + j) * 32 + seg * 8);
            }
            *(uint4*)(sc_hi + row * 40 + seg * 8) = vh;
            *(uint4*)(sc_lo + row * 40 + seg * 8) = vl;
        }
    }
    __syncthreads();

    int lane = t & 63, w = t >> 6;
    int r = lane & 15, quad = lane >> 4;
    int ib = i0 + w * 32;            // this wave's 32 anchors (2 i-tiles)

    bf16x8 a_hi[2], a_lo[2];
    int gt_i[2][4];
    #pragma unroll
    for (int it = 0; it < 2; ++it) {
        int i = ib + it * 16 + r;
        bf16x8 zh = {0, 0, 0, 0, 0, 0, 0, 0};
        a_hi[it] = zh; a_lo[it] = zh;
        if (i < M) {
            a_hi[it] = *(const bf16x8*)(hi_g + ((size_t)b * N_ + i) * 32 + quad * 8);
            a_lo[it] = *(const bf16x8*)(lo_g + ((size_t)b * N_ + i) * 32 + quad * 8);
        }
        #pragma unroll
        for (int r4 = 0; r4 < 4; ++r4) {
            int ia = ib + it * 16 + quad * 4 + r4;
            gt_i[it][r4] = (ia < M) ? cg[b * N_ + ia] : -2;
        }
    }

    float best[2][4];
    int cnt[2][4];
    #pragma unroll
    for (int it = 0; it < 2; ++it)
        #pragma unroll
        for (int r4 = 0; r4 < 4; ++r4) { best[it][r4] = -INFINITY; cnt[it][r4] = 0; }

    int jrows = min(TJ, M - j0);
    int ntile = (jrows + 15) >> 4;
    for (int jt = 0; jt < ntile; ++jt) {
        int gtj = sg[jt * 16 + r];
        bf16x8 bh = *(const bf16x8*)(sc_hi + (jt * 16 + r) * 40 + quad * 8);
        bf16x8 bl = *(const bf16x8*)(sc_lo + (jt * 16 + r) * 40 + quad * 8);
        bool jv = (gtj >= 0);
        #pragma unroll
        for (int it = 0; it < 2; ++it) {
            f32x4 acc = {0.f, 0.f, 0.f, 0.f};
            acc = __builtin_amdgcn_mfma_f32_16x16x32_bf16(a_hi[it], bh, acc, 0, 0, 0);
            acc = __builtin_amdgcn_mfma_f32_16x16x32_bf16(a_hi[it], bl, acc, 0, 0, 0);
            acc = __builtin_amdgcn_mfma_f32_16x16x32_bf16(a_lo[it], bh, acc, 0, 0, 0);
            #pragma unroll
            for (int r4 = 0; r4 < 4; ++r4) {
                float s = acc[r4];
                bool same = (gtj == gt_i[it][r4]);
                float sm = (same || !jv) ? -INFINITY : s;
                best[it][r4] = fmaxf(best[it][r4], sm);
                cnt[it][r4] += same ? 1 : 0;   // self-pair included; fixed in combine
            }
        }
    }

    #pragma unroll
    for (int it = 0; it < 2; ++it) {
        #pragma unroll
        for (int r4 = 0; r4 < 4; ++r4) {
            float bb = best[it][r4];
            int cc = cnt[it][r4];
            #pragma unroll
            for (int mk = 1; mk < 16; mk <<= 1) {
                bb = fmaxf(bb, __shfl_xor(bb, mk));
                cc += __shfl_xor(cc, mk);
            }
            if (r == 0) {
                int ia = ib + it * 16 + quad * 4 + r4;
                if (ia < M) {
                    p_cnt[((size_t)b * N_ + ia) * NCHJ + blockIdx.y] = (unsigned short)cc;
                    if (bb > -INFINITY) atomicMax(&bestArr[b * N_ + ia], fmap(bb));
                }
            }
        }
    }
}

// ---------------- Kernel 3: combine — one wave per anchor, no global atomics ----------------
__global__ __launch_bounds__(256) void k_combine(const unsigned short* __restrict__ hi_g,
                                                 const unsigned short* __restrict__ lo_g,
                                                 const int* __restrict__ cg,
                                                 const int* __restrict__ clist,
                                                 const int* __restrict__ Marr,
                                                 const float* __restrict__ pos_rand,
                                                 const unsigned short* __restrict__ p_cnt,
                                                 const unsigned* __restrict__ bestArr,
                                                 float* __restrict__ cArr,
                                                 int* __restrict__ vArr) {
    int b = blockIdx.y;
    int M = Marr[b];
    int t = threadIdx.x;
    int w = t >> 6, lane = t & 63;
    int i = blockIdx.x * 4 + w;           // this wave's anchor (wave-uniform)

    if (i >= M) return;                    // wave-uniform

    float contrib = 0.0f;
    int vflag = 0;

    int nchj = (M + TJ - 1) / TJ;
    int ich = i / TJ;
    const unsigned short* pc = p_cnt + ((size_t)b * N_ + i) * NCHJ;
    int c_s = 0;
    if (lane < nchj) c_s = (int)pc[lane] - (lane == ich ? 1 : 0);  // self removed
    // inclusive 64-lane scan
    int P = c_s;
    #pragma unroll
    for (int off = 1; off < 64; off <<= 1) {
        int n = __shfl_up(P, off);
        if (lane >= off) P += n;
    }
    int num_pos = __shfl(P, 63);
    unsigned bu = bestArr[b * N_ + i];
    if (num_pos >= 1 && bu != NEG_INF_MAPPED) {   // wave-uniform
        float best = funmap(bu);
        int orig = clist[b * N_ + i];
        float u = pos_rand[b * N_ + orig];
        int pcx = (int)floorf(u * (float)num_pos);   // matches jnp f32 math
        int hi2 = num_pos - 1;
        pcx = pcx < 0 ? 0 : (pcx > hi2 ? hi2 : pcx);
        int target = pcx + 1;
        // first chunk where inclusive prefix reaches target
        unsigned long long selm = __ballot(P >= target);
        int sstar = __ffsll((unsigned long long)selm) - 1;
        int c0 = (sstar > 0) ? __shfl(P, sstar - 1) : 0;
        int need = target - c0;       // wave-uniform, >= 1
        int jstart = sstar * TJ;
        int jend = min(jstart + TJ, M);
        int ga = cg[b * N_ + i];
        int posj = -1;
        #pragma unroll
        for (int k = 0; k < 4; ++k) {
            if (posj >= 0) continue;
            int j = jstart + k * 64 + lane;
            bool flag = (j < jend) && (cg[b * N_ + j] == ga) && (j != i);
            unsigned long long mk = __ballot(flag);
            int tot = __popcll(mk);
            if (need <= tot) {
                int pfx = __popcll(mk & ((1ull << lane) - 1ull));
                unsigned long long sel = __ballot(flag && (pfx == need - 1));
                posj = jstart + k * 64 + (__ffsll((unsigned long long)sel) - 1);
            } else {
                need -= tot;
            }
        }
        // lane-parallel dot over the 16 packed-bf16 pairs (fp32 reconstruct)
        float part = 0.0f;
        if (lane < 16) {
            unsigned xh = ((const unsigned*)(hi_g + ((size_t)b * N_ + i) * 32))[lane];
            unsigned xl = ((const unsigned*)(lo_g + ((size_t)b * N_ + i) * 32))[lane];
            unsigned yh = ((const unsigned*)(hi_g + ((size_t)b * N_ + posj) * 32))[lane];
            unsigned yl = ((const unsigned*)(lo_g + ((size_t)b * N_ + posj) * 32))[lane];
            float a0, a1, b0, b1, c0f, c1f, d0, d1;
            bf2x(xh, a0, a1); bf2x(xl, b0, b1);
            bf2x(yh, c0f, c1f); bf2x(yl, d0, d1);
            part = fmaf(a0 + b0, c0f + d0, (a1 + b1) * (c1f + d1));
        }
        #pragma unroll
        for (int mk2 = 1; mk2 < 16; mk2 <<= 1) part += __shfl_xor(part, mk2);
        float dot = part;
        float pos_d = sqrtf(fmaxf(2.f - 2.f * dot, 0.f) + 1e-12f);
        float neg_d = sqrtf(fmaxf(2.f - 2.f * best, 0.f) + 1e-12f);
        contrib = fmaxf(pos_d - neg_d + MARGIN_, 0.0f);
        vflag = 1;
    }

    if (lane == 0) {
        cArr[b * N_ + i] = contrib;
        vArr[b * N_ + i] = vflag;
    }
}

// ---------------- Kernel 4: final reduction (single block) ----------------
__global__ __launch_bounds__(1024) void k_final(const float* __restrict__ cArr,
                                                const int* __restrict__ vArr,
                                                const int* __restrict__ Marr,
                                                float* __restrict__ out) {
    int tid = threadIdx.x;
    float tv = 0.0f;
    int tc = 0;
    #pragma unroll
    for (int b = 0; b < B_; ++b) {
        int M = Marr[b];
        for (int i = tid; i < M; i += 1024) {
            tv += cArr[b * N_ + i];
            tc += vArr[b * N_ + i];
        }
    }
    #pragma unroll
    for (int off = 32; off > 0; off >>= 1) {
        tv += __shfl_down(tv, off);
        tc += __shfl_down(tc, off);
    }
    __shared__ float sv[16];
    __shared__ int scnt[16];
    int lane = tid & 63, w = tid >> 6;
    if (lane == 0) { sv[w] = tv; scnt[w] = tc; }
    __syncthreads();
    if (tid == 0) {
        float T = 0.0f; int C = 0;
        #pragma unroll
        for (int k = 0; k < 16; ++k) { T += sv[k]; C += scnt[k]; }
        out[0] = (C > 0) ? (T / (float)C) : 0.0f;
    }
}

// ---------------- launch ----------------
extern "C" void kernel_launch(void* const* d_in, const int* in_sizes, int n_in,
                              void* d_out, int out_size, void* d_ws, size_t ws_size,
                              hipStream_t stream) {
    const float* pred     = (const float*)d_in[0];
    const float* pos_rand = (const float*)d_in[1];
    const int*   gt       = (const int*)d_in[2];
    const int*   fg       = (const int*)d_in[3];
    float* out = (float*)d_out;

    char* ws = (char*)d_ws;
    // layout (bytes):
    //   hi_g     : 0         .. 1,638,400   (B*N*32 bf16)
    //   lo_g     : 1,638,400 .. 3,276,800
    //   clist    : 3,276,800 .. 3,379,200   (B*N i32)
    //   cg       : 3,379,200 .. 3,481,600   (B*N i32)
    //   Marr     : 3,481,600 .. 3,481,664
    //   bestArr  : 3,482,688 .. 3,585,088   (B*N u32)
    //   p_cnt    : 3,585,088 .. 4,865,088   (B*N*NCHJ u16)
    //   cArr     : 4,865,088 .. 4,967,488   (B*N f32)
    //   vArr     : 4,967,488 .. 5,069,888   (B*N i32)
    unsigned short* hi_g    = (unsigned short*)(ws);
    unsigned short* lo_g    = (unsigned short*)(ws + 1638400);
    int*            clist   = (int*)(ws + 3276800);
    int*            cg      = (int*)(ws + 3379200);
    int*            Marr    = (int*)(ws + 3481600);
    unsigned*       bestArr = (unsigned*)(ws + 3482688);
    unsigned short* p_cnt   = (unsigned short*)(ws + 3585088);
    float*          cArr    = (float*)(ws + 4865088);
    int*            vArr    = (int*)(ws + 4967488);

    dim3 gpr(NCC, B_);
    k_prep<<<gpr, 256, 0, stream>>>(pred, gt, fg, hi_g, lo_g, clist, cg, Marr, bestArr);
    dim3 gp((N_ + TI - 1) / TI, (N_ + TJ - 1) / TJ, B_);
    k_pass<<<gp, 256, 0, stream>>>(hi_g, lo_g, cg, Marr, p_cnt, bestArr);
    dim3 gc((N_ + 3) / 4, B_);
    k_combine<<<gc, 256, 0, stream>>>(hi_g, lo_g, cg, clist, Marr, pos_rand, p_cnt, bestArr, cArr, vArr);
    k_final<<<1, 1024, 0, stream>>>(cArr, vArr, Marr, out);
}